// Round 2
// baseline (1028.613 us; speedup 1.0000x reference)
//
#include <hip/hip_runtime.h>
#include <hip/hip_bf16.h>

// Problem constants (reference: B,S,H,NH,HD = 2,2048,4096,32,128)
constexpr int Bc  = 2;
constexpr int Sc  = 2048;
constexpr int Hc  = 4096;
constexpr int NHc = 32;
constexpr int HDc = 128;

typedef __attribute__((ext_vector_type(8))) __bf16 bf16x8;
typedef __attribute__((ext_vector_type(4))) __bf16 bf16x4;
typedef __attribute__((ext_vector_type(4))) float  f32x4;

#if defined(__has_builtin)
#if __has_builtin(__builtin_amdgcn_global_load_lds)
#define HAS_GLL 1
#endif
#endif
#ifndef HAS_GLL
#define HAS_GLL 0
#endif

// async global->LDS, 16B per lane. lds base must be wave-uniform; HW adds lane*16.
__device__ __forceinline__ void gll16(const __bf16* g, __bf16* lds_base, int lane) {
#if HAS_GLL
    __builtin_amdgcn_global_load_lds((const __attribute__((address_space(1))) void*)g,
                                     (__attribute__((address_space(3))) void*)lds_base,
                                     16, 0, 0);
#else
    *(int4*)(lds_base + lane * 8) = *(const int4*)g;
#endif
}

// ---------------------------------------------------------------------------
// fp32 -> bf16 conversion
// ---------------------------------------------------------------------------
__global__ void cvt_f32_bf16(const float* __restrict__ in, __bf16* __restrict__ out, int n) {
    int i = (blockIdx.x * blockDim.x + threadIdx.x) * 4;
    if (i >= n) return;
    const float4 v = *(const float4*)(in + i);
    bf16x4 o;
    o[0] = (__bf16)v.x; o[1] = (__bf16)v.y; o[2] = (__bf16)v.z; o[3] = (__bf16)v.w;
    *(bf16x4*)(out + i) = o;
}

// Build fused KV weight: rows 0..127 = Wk, rows 128..255 = Wv  (256 x 4096)
__global__ void build_wkv(const float* __restrict__ Wk, const float* __restrict__ Wv,
                          __bf16* __restrict__ out) {
    int i = (blockIdx.x * blockDim.x + threadIdx.x) * 4;
    if (i >= 256 * Hc) return;
    int row = i >> 12;
    int col = i & (Hc - 1);
    const float* src = (row < HDc) ? (Wk + (long)row * Hc + col)
                                   : (Wv + (long)(row - HDc) * Hc + col);
    const float4 v = *(const float4*)src;
    bf16x4 o;
    o[0] = (__bf16)v.x; o[1] = (__bf16)v.y; o[2] = (__bf16)v.z; o[3] = (__bf16)v.w;
    *(bf16x4*)(out + i) = o;
}

// ---------------------------------------------------------------------------
// NT GEMM (m97 structure): C[m][n] = sum_k A[m][k]*B[n][k], 128x128 tile, BK=32,
// 256 thr (4 waves, 2x2 of 64x64), global_load_lds width-16 staging, unpadded LDS.
// ---------------------------------------------------------------------------
template <typename OUT>
__global__ __launch_bounds__(256)
void gemm_bt(const __bf16* __restrict__ A, const __bf16* __restrict__ B,
             OUT* __restrict__ C, int M, int N, int K) {
    __shared__ __bf16 As[128][32];
    __shared__ __bf16 Bs[128][32];

    const int tid  = threadIdx.x;
    const int wave = tid >> 6, lane = tid & 63;
    const int lrow = lane & 15, quad = lane >> 4;
    const int m0   = blockIdx.y * 128;
    const int n0   = blockIdx.x * 128;
    const int wr   = (wave >> 1) * 64;
    const int wc   = (wave & 1) * 64;

    f32x4 acc[4][4] = {};

    // staging: wave w covers rows [w*32, w*32+32) in two 16-row chunks;
    // lane -> (row = lane>>2, col = (lane&3)*8)  == lds offset lane*16B.
    const int srow = lane >> 2;
    const int scol = (lane & 3) * 8;
    const __bf16* Ap = A + (long)(m0 + wave * 32 + srow) * K + scol;
    const __bf16* Bp = B + (long)(n0 + wave * 32 + srow) * K + scol;
    __bf16* lA0 = &As[wave * 32][0];
    __bf16* lA1 = &As[wave * 32 + 16][0];
    __bf16* lB0 = &Bs[wave * 32][0];
    __bf16* lB1 = &Bs[wave * 32 + 16][0];
    const long r16K = (long)16 * K;

    const int nk = K >> 5;
    for (int kt = 0; kt < nk; ++kt) {
        const long ko = (long)kt * 32;
        __syncthreads();
        gll16(Ap + ko,        lA0, lane);
        gll16(Ap + r16K + ko, lA1, lane);
        gll16(Bp + ko,        lB0, lane);
        gll16(Bp + r16K + ko, lB1, lane);
        __syncthreads();

        bf16x8 af[4], bfv[4];
#pragma unroll
        for (int i = 0; i < 4; ++i) af[i]  = *(const bf16x8*)&As[wr + i * 16 + lrow][quad * 8];
#pragma unroll
        for (int j = 0; j < 4; ++j) bfv[j] = *(const bf16x8*)&Bs[wc + j * 16 + lrow][quad * 8];
#pragma unroll
        for (int i = 0; i < 4; ++i)
#pragma unroll
            for (int j = 0; j < 4; ++j)
                acc[i][j] = __builtin_amdgcn_mfma_f32_16x16x32_bf16(af[i], bfv[j], acc[i][j], 0, 0, 0);
    }

#pragma unroll
    for (int i = 0; i < 4; ++i) {
        const int row = m0 + wr + i * 16 + quad * 4;
#pragma unroll
        for (int j = 0; j < 4; ++j) {
            const int col = n0 + wc + j * 16 + lrow;
            OUT* cp = C + (long)row * N + col;
#pragma unroll
            for (int r = 0; r < 4; ++r) cp[(long)r * N] = (OUT)acc[i][j][r];
        }
    }
}

// 64x64-tile variant for the skinny KV GEMM (N=256): 256 blocks instead of 64.
template <typename OUT>
__global__ __launch_bounds__(256)
void gemm_bt64(const __bf16* __restrict__ A, const __bf16* __restrict__ B,
               OUT* __restrict__ C, int M, int N, int K) {
    __shared__ __bf16 As[64][32];
    __shared__ __bf16 Bs[64][32];

    const int tid  = threadIdx.x;
    const int wave = tid >> 6, lane = tid & 63;
    const int lrow = lane & 15, quad = lane >> 4;
    const int m0   = blockIdx.y * 64;
    const int n0   = blockIdx.x * 64;
    const int wr   = (wave >> 1) * 32;
    const int wc   = (wave & 1) * 32;

    f32x4 acc[2][2] = {};

    const int srow = lane >> 2;
    const int scol = (lane & 3) * 8;
    const __bf16* Ap = A + (long)(m0 + wave * 16 + srow) * K + scol;
    const __bf16* Bp = B + (long)(n0 + wave * 16 + srow) * K + scol;
    __bf16* lA = &As[wave * 16][0];
    __bf16* lB = &Bs[wave * 16][0];

    const int nk = K >> 5;
    for (int kt = 0; kt < nk; ++kt) {
        const long ko = (long)kt * 32;
        __syncthreads();
        gll16(Ap + ko, lA, lane);
        gll16(Bp + ko, lB, lane);
        __syncthreads();

        bf16x8 af[2], bfv[2];
#pragma unroll
        for (int i = 0; i < 2; ++i) af[i]  = *(const bf16x8*)&As[wr + i * 16 + lrow][quad * 8];
#pragma unroll
        for (int j = 0; j < 2; ++j) bfv[j] = *(const bf16x8*)&Bs[wc + j * 16 + lrow][quad * 8];
#pragma unroll
        for (int i = 0; i < 2; ++i)
#pragma unroll
            for (int j = 0; j < 2; ++j)
                acc[i][j] = __builtin_amdgcn_mfma_f32_16x16x32_bf16(af[i], bfv[j], acc[i][j], 0, 0, 0);
    }

#pragma unroll
    for (int i = 0; i < 2; ++i) {
        const int row = m0 + wr + i * 16 + quad * 4;
#pragma unroll
        for (int j = 0; j < 2; ++j) {
            const int col = n0 + wc + j * 16 + lrow;
            OUT* cp = C + (long)row * N + col;
#pragma unroll
            for (int r = 0; r < 4; ++r) cp[(long)r * N] = (OUT)acc[i][j][r];
        }
    }
}

// ---------------------------------------------------------------------------
// RoPE on Q (in-place), scale folded in.
// ---------------------------------------------------------------------------
__global__ void rope_q(__bf16* __restrict__ Q, const float* __restrict__ cosb,
                       const float* __restrict__ sinb, float scale) {
    int gid  = blockIdx.x * blockDim.x + threadIdx.x;
    int row  = gid >> 8;
    int rem  = gid & 255;
    int h    = rem >> 3;
    int dblk = (rem & 7) * 8;
    int s    = row & (Sc - 1);
    __bf16* p = Q + (long)row * Hc + h * HDc;
    const float* cp = cosb + s * HDc;
    const float* sp = sinb + s * HDc;
    bf16x8 lo = *(bf16x8*)(p + dblk);
    bf16x8 hi = *(bf16x8*)(p + dblk + 64);
    bf16x8 olo, ohi;
#pragma unroll
    for (int j = 0; j < 8; ++j) {
        float ql = (float)lo[j], qh = (float)hi[j];
        float cl = cp[dblk + j],      sl = sp[dblk + j];
        float ch = cp[dblk + 64 + j], sh = sp[dblk + 64 + j];
        olo[j] = (__bf16)((ql * cl - qh * sl) * scale);
        ohi[j] = (__bf16)((qh * ch + ql * sh) * scale);
    }
    *(bf16x8*)(p + dblk)      = olo;
    *(bf16x8*)(p + dblk + 64) = ohi;
}

__global__ void rope_k(__bf16* __restrict__ KV, const float* __restrict__ cosb,
                       const float* __restrict__ sinb) {
    int gid  = blockIdx.x * blockDim.x + threadIdx.x;
    int row  = gid >> 3;
    int dblk = (gid & 7) * 8;
    int s    = row & (Sc - 1);
    __bf16* p = KV + (long)row * 256;
    const float* cp = cosb + s * HDc;
    const float* sp = sinb + s * HDc;
    bf16x8 lo = *(bf16x8*)(p + dblk);
    bf16x8 hi = *(bf16x8*)(p + dblk + 64);
    bf16x8 olo, ohi;
#pragma unroll
    for (int j = 0; j < 8; ++j) {
        float ql = (float)lo[j], qh = (float)hi[j];
        float cl = cp[dblk + j],      sl = sp[dblk + j];
        float ch = cp[dblk + 64 + j], sh = sp[dblk + 64 + j];
        olo[j] = (__bf16)(ql * cl - qh * sl);
        ohi[j] = (__bf16)(qh * ch + ql * sh);
    }
    *(bf16x8*)(p + dblk)      = olo;
    *(bf16x8*)(p + dblk + 64) = ohi;
}

// V transpose: Vt[b][d][s] = KV[(b*S+s)*256 + 128 + d]
__global__ void vtrans(const __bf16* __restrict__ KV, __bf16* __restrict__ Vt) {
    int gid = blockIdx.x * blockDim.x + threadIdx.x;
    int b   = gid >> 18;
    int r   = gid & (HDc * Sc - 1);
    int d   = r >> 11;
    int s   = r & (Sc - 1);
    Vt[gid] = KV[((long)(b * Sc + s)) * 256 + HDc + d];
}

// ---------------------------------------------------------------------------
// Causal MQA flash attention v2.
// grid: (S/128, B*NH), heavy-qt-first. 256 thr = 4 waves; wave owns 32 Q rows
// (2 x 16-row frags). KV tiles of 64. Row-sum l via ones-rows appended to V.
// ---------------------------------------------------------------------------
__global__ __launch_bounds__(256, 3)
void attn(const __bf16* __restrict__ Q,    // (B*S, H), rope'd & pre-scaled
          const __bf16* __restrict__ KV,   // (B*S, 256): cols 0..127 = K (rope'd)
          const __bf16* __restrict__ Vt,   // (B, HD, S)
          __bf16* __restrict__ O) {        // (B*S, H)
    const int qt   = (gridDim.x - 1) - blockIdx.x;   // heavy blocks first
    const int bh   = blockIdx.y;
    const int b    = bh >> 5, h = bh & 31;
    const int tid  = threadIdx.x;
    const int wave = tid >> 6, lane = tid & 63;
    const int lrow = lane & 15, quad = lane >> 4;

    __shared__ __bf16 Ks[64][136];    // 64 kv x 128 d (+8 pad)
    __shared__ __bf16 Vs[144][72];    // rows 0..127: d x kv; rows 128..143: 1.0
    __shared__ __bf16 Ps[4][16][72];  // per-wave P tile (reused for both halves)

    // ones rows for the l-accumulator MFMA
    for (int idx = tid; idx < 16 * 72; idx += 256)
        Vs[128 + idx / 72][idx % 72] = (__bf16)1.0f;

    const int q0 = qt * 128 + wave * 32;   // first q row of this wave

    bf16x8 aq[2][4];
#pragma unroll
    for (int qq = 0; qq < 2; ++qq) {
        const __bf16* qp = Q + (long)(b * Sc + q0 + qq * 16 + lrow) * Hc + h * HDc + quad * 8;
#pragma unroll
        for (int c = 0; c < 4; ++c) aq[qq][c] = *(const bf16x8*)(qp + c * 32);
    }

    f32x4 o[2][8] = {};
    f32x4 lac[2] = {};
    float mst[2][4];
#pragma unroll
    for (int qq = 0; qq < 2; ++qq)
#pragma unroll
        for (int r = 0; r < 4; ++r) mst[qq][r] = -3.0e38f;

    const int nt = 2 * qt + 2;
    for (int kt = 0; kt < nt; ++kt) {
        __syncthreads();
        // stage K tile (64x128) and Vt tile (128x64)
#pragma unroll
        for (int rr = 0; rr < 4; ++rr) {
            int e = rr * 2048 + tid * 8;
            int row = e >> 7, col = e & 127;
            *(int4*)&Ks[row][col] =
                *(const int4*)(KV + (long)(b * Sc + kt * 64 + row) * 256 + col);
        }
#pragma unroll
        for (int rr = 0; rr < 4; ++rr) {
            int e = rr * 2048 + tid * 8;
            int row = e >> 6, col = e & 63;
            *(int4*)&Vs[row][col] =
                *(const int4*)(Vt + (long)(b * HDc + row) * Sc + kt * 64 + col);
        }
        __syncthreads();

        bf16x8 ap[2][2];
#pragma unroll
        for (int qq = 0; qq < 2; ++qq) {
            // S = Q K^T  (16 q x 64 kv)
            f32x4 sc[4] = {};
#pragma unroll
            for (int ct = 0; ct < 4; ++ct) {
#pragma unroll
                for (int c = 0; c < 4; ++c) {
                    bf16x8 bk = *(const bf16x8*)&Ks[ct * 16 + lrow][c * 32 + quad * 8];
                    sc[ct] = __builtin_amdgcn_mfma_f32_16x16x32_bf16(aq[qq][c], bk, sc[ct], 0, 0, 0);
                }
            }

            if (kt * 64 + 63 > q0 + qq * 16) {  // tile may cross the diagonal
#pragma unroll
                for (int ct = 0; ct < 4; ++ct) {
                    int kv = kt * 64 + ct * 16 + lrow;
#pragma unroll
                    for (int r = 0; r < 4; ++r) {
                        int qr = q0 + qq * 16 + quad * 4 + r;
                        if (kv > qr) sc[ct][r] = -3.0e38f;
                    }
                }
            }

            // online softmax (sum via ones-MFMA later; only max needs shuffles)
            float mnewv[4], alf[4];
#pragma unroll
            for (int r = 0; r < 4; ++r) {
                float mx = fmaxf(fmaxf(sc[0][r], sc[1][r]), fmaxf(sc[2][r], sc[3][r]));
#pragma unroll
                for (int off = 1; off < 16; off <<= 1) mx = fmaxf(mx, __shfl_xor(mx, off, 64));
                float mnew = fmaxf(mst[qq][r], mx);
                alf[r]   = __expf(mst[qq][r] - mnew);
                mst[qq][r] = mnew;
                mnewv[r] = mnew;
            }
#pragma unroll
            for (int ct = 0; ct < 4; ++ct)
#pragma unroll
                for (int r = 0; r < 4; ++r)
                    sc[ct][r] = __expf(sc[ct][r] - mnewv[r]);
#pragma unroll
            for (int dt = 0; dt < 8; ++dt)
#pragma unroll
                for (int r = 0; r < 4; ++r) o[qq][dt][r] *= alf[r];
#pragma unroll
            for (int r = 0; r < 4; ++r) lac[qq][r] *= alf[r];

            // P -> LDS (C-layout -> A-layout), per-wave buffer, no block barrier
#pragma unroll
            for (int ct = 0; ct < 4; ++ct)
#pragma unroll
                for (int r = 0; r < 4; ++r)
                    Ps[wave][quad * 4 + r][ct * 16 + lrow] = (__bf16)sc[ct][r];
#pragma unroll
            for (int ks = 0; ks < 2; ++ks)
                ap[qq][ks] = *(const bf16x8*)&Ps[wave][lrow][ks * 32 + quad * 8];
        }

        // O += P V  (V-frags shared across both q halves)
#pragma unroll
        for (int dt = 0; dt < 8; ++dt) {
#pragma unroll
            for (int ks = 0; ks < 2; ++ks) {
                bf16x8 bv = *(const bf16x8*)&Vs[dt * 16 + lrow][ks * 32 + quad * 8];
#pragma unroll
                for (int qq = 0; qq < 2; ++qq)
                    o[qq][dt] = __builtin_amdgcn_mfma_f32_16x16x32_bf16(ap[qq][ks], bv, o[qq][dt], 0, 0, 0);
            }
        }
        // l += P . ones
#pragma unroll
        for (int ks = 0; ks < 2; ++ks) {
            bf16x8 bv = *(const bf16x8*)&Vs[128 + lrow][ks * 32 + quad * 8];
#pragma unroll
            for (int qq = 0; qq < 2; ++qq)
                lac[qq] = __builtin_amdgcn_mfma_f32_16x16x32_bf16(ap[qq][ks], bv, lac[qq], 0, 0, 0);
        }
    }

    // epilogue
#pragma unroll
    for (int qq = 0; qq < 2; ++qq)
#pragma unroll
        for (int r = 0; r < 4; ++r) {
            float inv = 1.f / lac[qq][r];
            int qr = q0 + qq * 16 + quad * 4 + r;
            __bf16* op = O + (long)(b * Sc + qr) * Hc + h * HDc;
#pragma unroll
            for (int dt = 0; dt < 8; ++dt) op[dt * 16 + lrow] = (__bf16)(o[qq][dt][r] * inv);
        }
}

// ---------------------------------------------------------------------------
extern "C" void kernel_launch(void* const* d_in, const int* in_sizes, int n_in,
                              void* d_out, int out_size, void* d_ws, size_t ws_size,
                              hipStream_t stream) {
    const float* hs   = (const float*)d_in[0];
    const float* cosb = (const float*)d_in[1];
    const float* sinb = (const float*)d_in[2];
    const float* Wq   = (const float*)d_in[3];
    const float* Wk   = (const float*)d_in[4];
    const float* Wv   = (const float*)d_in[5];
    const float* Wd   = (const float*)d_in[6];
    float* out = (float*)d_out;

    char* ws = (char*)d_ws;
    const long SZ_HS  = (long)Bc * Sc * Hc * 2;      // 32MB
    const long SZ_W   = (long)Hc * Hc * 2;           // 32MB
    const long SZ_KV  = (long)Bc * Sc * 256 * 2;     // 2MB
    __bf16* hs16  = (__bf16*)(ws);
    __bf16* wq16  = (__bf16*)(ws + SZ_HS);
    __bf16* wkv16 = (__bf16*)(ws + SZ_HS + SZ_W);
    __bf16* q16   = (__bf16*)(ws + SZ_HS + SZ_W + SZ_KV);
    __bf16* kv16  = (__bf16*)(ws + SZ_HS + SZ_W + SZ_KV + SZ_HS);
    __bf16* vt16  = (__bf16*)(ws + SZ_HS + SZ_W + SZ_KV + SZ_HS + SZ_KV);
    __bf16* att16 = hs16;   // reuse: hidden dead after Q/KV GEMMs
    __bf16* wd16  = wq16;   // reuse: Wq dead after Q GEMM

    const int nHS = Bc * Sc * Hc;   // 16M
    const int nW  = Hc * Hc;        // 16M

    cvt_f32_bf16<<<nHS / 1024, 256, 0, stream>>>(hs, hs16, nHS);
    cvt_f32_bf16<<<nW / 1024, 256, 0, stream>>>(Wq, wq16, nW);
    build_wkv<<<(256 * Hc) / 1024, 256, 0, stream>>>(Wk, Wv, wkv16);

    gemm_bt<__bf16><<<dim3(Hc / 128, (Bc * Sc) / 128), 256, 0, stream>>>(
        hs16, wq16, q16, Bc * Sc, Hc, Hc);
    gemm_bt64<__bf16><<<dim3(256 / 64, (Bc * Sc) / 64), 256, 0, stream>>>(
        hs16, wkv16, kv16, Bc * Sc, 256, Hc);

    cvt_f32_bf16<<<nW / 1024, 256, 0, stream>>>(Wd, wd16, nW);  // after Q GEMM

    const float scale = 0.08838834764831845f;  // 1/sqrt(128)
    rope_q<<<(Bc * Sc * NHc * 8) / 256, 256, 0, stream>>>(q16, cosb, sinb, scale);
    rope_k<<<(Bc * Sc * 8) / 256, 256, 0, stream>>>(kv16, cosb, sinb);
    vtrans<<<(Bc * HDc * Sc) / 256, 256, 0, stream>>>(kv16, vt16);

    attn<<<dim3(Sc / 128, Bc * NHc), 256, 0, stream>>>(q16, kv16, vt16, att16);

    gemm_bt<float><<<dim3(Hc / 128, (Bc * Sc) / 128), 256, 0, stream>>>(
        att16, wd16, out, Bc * Sc, Hc, Hc);
}

// Round 3
// 797.585 us; speedup vs baseline: 1.2897x; 1.2897x over previous
//
#include <hip/hip_runtime.h>
#include <hip/hip_bf16.h>

// Problem constants (reference: B,S,H,NH,HD = 2,2048,4096,32,128)
constexpr int Bc  = 2;
constexpr int Sc  = 2048;
constexpr int Hc  = 4096;
constexpr int NHc = 32;
constexpr int HDc = 128;

typedef __attribute__((ext_vector_type(8))) __bf16 bf16x8;
typedef __attribute__((ext_vector_type(4))) __bf16 bf16x4;
typedef __attribute__((ext_vector_type(4))) float  f32x4;

#if defined(__has_builtin)
#if __has_builtin(__builtin_amdgcn_global_load_lds)
#define HAS_GLL 1
#endif
#endif
#ifndef HAS_GLL
#define HAS_GLL 0
#endif

// async global->LDS, 16B per lane. lds base must be wave-uniform; HW adds lane*16.
__device__ __forceinline__ void gll16(const __bf16* g, __bf16* lds_base, int lane) {
#if HAS_GLL
    __builtin_amdgcn_global_load_lds((const __attribute__((address_space(1))) void*)g,
                                     (__attribute__((address_space(3))) void*)lds_base,
                                     16, 0, 0);
#else
    *(int4*)(lds_base + lane * 8) = *(const int4*)g;
#endif
}

// ---------------------------------------------------------------------------
// fp32 -> bf16 conversion
// ---------------------------------------------------------------------------
__global__ void cvt_f32_bf16(const float* __restrict__ in, __bf16* __restrict__ out, int n) {
    int i = (blockIdx.x * blockDim.x + threadIdx.x) * 4;
    if (i >= n) return;
    const float4 v = *(const float4*)(in + i);
    bf16x4 o;
    o[0] = (__bf16)v.x; o[1] = (__bf16)v.y; o[2] = (__bf16)v.z; o[3] = (__bf16)v.w;
    *(bf16x4*)(out + i) = o;
}

// Build fused KV weight: rows 0..127 = Wk, rows 128..255 = Wv  (256 x 4096)
__global__ void build_wkv(const float* __restrict__ Wk, const float* __restrict__ Wv,
                          __bf16* __restrict__ out) {
    int i = (blockIdx.x * blockDim.x + threadIdx.x) * 4;
    if (i >= 256 * Hc) return;
    int row = i >> 12;
    int col = i & (Hc - 1);
    const float* src = (row < HDc) ? (Wk + (long)row * Hc + col)
                                   : (Wv + (long)(row - HDc) * Hc + col);
    const float4 v = *(const float4*)src;
    bf16x4 o;
    o[0] = (__bf16)v.x; o[1] = (__bf16)v.y; o[2] = (__bf16)v.z; o[3] = (__bf16)v.w;
    *(bf16x4*)(out + i) = o;
}

// ---------------------------------------------------------------------------
// NT GEMM v3: C[m][n] = sum_k A[m][k]*B[n][k]. 128x128 tile, BK=64, 256 thr
// (4 waves, 2x2 of 64x64), gll16 staging with XOR-swizzled LDS columns
// (phys col16 = logical ^ (row&7)) -> conflict-free ds_read_b128.
// ---------------------------------------------------------------------------
template <typename OUT>
__global__ __launch_bounds__(256)
void gemm_bt(const __bf16* __restrict__ A, const __bf16* __restrict__ B,
             OUT* __restrict__ C, int M, int N, int K) {
    __shared__ __bf16 As[128][64];
    __shared__ __bf16 Bs[128][64];

    const int tid  = threadIdx.x;
    const int wave = tid >> 6, lane = tid & 63;
    const int lrow = lane & 15, quad = lane >> 4;
    const int m0   = blockIdx.y * 128;
    const int n0   = blockIdx.x * 128;
    const int wr   = (wave >> 1) * 64;
    const int wc   = (wave & 1) * 64;

    f32x4 acc[4][4] = {};

    // staging slots: chunk (wave*4+it) covers LDS bytes [chunk*1024, +1024)
    int srow[4], scol[4];
#pragma unroll
    for (int it = 0; it < 4; ++it) {
        int e = (wave * 4 + it) * 1024 + lane * 16;  // byte offset in 16KB tile
        int r = e >> 7;                              // row (128B rows)
        int cb = (e >> 4) & 7;                       // physical col16
        srow[it] = r;
        scol[it] = ((cb ^ (r & 7)) * 8);             // logical elem col
    }
    const __bf16* Ab = A + (long)m0 * K;
    const __bf16* Bb = B + (long)n0 * K;

    // frag-read physical columns (elem offsets), c = 0,1
    const int fcol0 = ((quad ^ (lrow & 7)) << 3);
    const int fcol1 = (((4 | quad) ^ (lrow & 7)) << 3);

    const int nk = K >> 6;
    for (int kt = 0; kt < nk; ++kt) {
        const long k0 = (long)kt * 64;
        __syncthreads();
#pragma unroll
        for (int it = 0; it < 4; ++it)
            gll16(Ab + (long)srow[it] * K + k0 + scol[it], &As[0][0] + (wave * 4 + it) * 512, lane);
#pragma unroll
        for (int it = 0; it < 4; ++it)
            gll16(Bb + (long)srow[it] * K + k0 + scol[it], &Bs[0][0] + (wave * 4 + it) * 512, lane);
        __syncthreads();

#pragma unroll
        for (int c = 0; c < 2; ++c) {
            const int fc = c ? fcol1 : fcol0;
            bf16x8 af[4], bfv[4];
#pragma unroll
            for (int i = 0; i < 4; ++i) af[i]  = *(const bf16x8*)&As[wr + i * 16 + lrow][fc];
#pragma unroll
            for (int j = 0; j < 4; ++j) bfv[j] = *(const bf16x8*)&Bs[wc + j * 16 + lrow][fc];
#pragma unroll
            for (int i = 0; i < 4; ++i)
#pragma unroll
                for (int j = 0; j < 4; ++j)
                    acc[i][j] = __builtin_amdgcn_mfma_f32_16x16x32_bf16(af[i], bfv[j], acc[i][j], 0, 0, 0);
        }
    }

#pragma unroll
    for (int i = 0; i < 4; ++i) {
        const int row = m0 + wr + i * 16 + quad * 4;
#pragma unroll
        for (int j = 0; j < 4; ++j) {
            const int col = n0 + wc + j * 16 + lrow;
            OUT* cp = C + (long)row * N + col;
#pragma unroll
            for (int r = 0; r < 4; ++r) cp[(long)r * N] = (OUT)acc[i][j][r];
        }
    }
}

// 64x64-tile variant (KV GEMM, N=256 -> 256 blocks), same swizzled structure.
template <typename OUT>
__global__ __launch_bounds__(256)
void gemm_bt64(const __bf16* __restrict__ A, const __bf16* __restrict__ B,
               OUT* __restrict__ C, int M, int N, int K) {
    __shared__ __bf16 As[64][64];
    __shared__ __bf16 Bs[64][64];

    const int tid  = threadIdx.x;
    const int wave = tid >> 6, lane = tid & 63;
    const int lrow = lane & 15, quad = lane >> 4;
    const int m0   = blockIdx.y * 64;
    const int n0   = blockIdx.x * 64;
    const int wr   = (wave >> 1) * 32;
    const int wc   = (wave & 1) * 32;

    f32x4 acc[2][2] = {};

    int srow[2], scol[2];
#pragma unroll
    for (int it = 0; it < 2; ++it) {
        int e = (wave * 2 + it) * 1024 + lane * 16;
        int r = e >> 7;
        int cb = (e >> 4) & 7;
        srow[it] = r;
        scol[it] = ((cb ^ (r & 7)) * 8);
    }
    const __bf16* Ab = A + (long)m0 * K;
    const __bf16* Bb = B + (long)n0 * K;

    const int fcol0 = ((quad ^ (lrow & 7)) << 3);
    const int fcol1 = (((4 | quad) ^ (lrow & 7)) << 3);

    const int nk = K >> 6;
    for (int kt = 0; kt < nk; ++kt) {
        const long k0 = (long)kt * 64;
        __syncthreads();
#pragma unroll
        for (int it = 0; it < 2; ++it)
            gll16(Ab + (long)srow[it] * K + k0 + scol[it], &As[0][0] + (wave * 2 + it) * 512, lane);
#pragma unroll
        for (int it = 0; it < 2; ++it)
            gll16(Bb + (long)srow[it] * K + k0 + scol[it], &Bs[0][0] + (wave * 2 + it) * 512, lane);
        __syncthreads();

#pragma unroll
        for (int c = 0; c < 2; ++c) {
            const int fc = c ? fcol1 : fcol0;
            bf16x8 af[2], bfv[2];
#pragma unroll
            for (int i = 0; i < 2; ++i) af[i]  = *(const bf16x8*)&As[wr + i * 16 + lrow][fc];
#pragma unroll
            for (int j = 0; j < 2; ++j) bfv[j] = *(const bf16x8*)&Bs[wc + j * 16 + lrow][fc];
#pragma unroll
            for (int i = 0; i < 2; ++i)
#pragma unroll
                for (int j = 0; j < 2; ++j)
                    acc[i][j] = __builtin_amdgcn_mfma_f32_16x16x32_bf16(af[i], bfv[j], acc[i][j], 0, 0, 0);
        }
    }

#pragma unroll
    for (int i = 0; i < 2; ++i) {
        const int row = m0 + wr + i * 16 + quad * 4;
#pragma unroll
        for (int j = 0; j < 2; ++j) {
            const int col = n0 + wc + j * 16 + lrow;
            OUT* cp = C + (long)row * N + col;
#pragma unroll
            for (int r = 0; r < 4; ++r) cp[(long)r * N] = (OUT)acc[i][j][r];
        }
    }
}

// ---------------------------------------------------------------------------
// RoPE on Q (in-place), scale folded in.
// ---------------------------------------------------------------------------
__global__ void rope_q(__bf16* __restrict__ Q, const float* __restrict__ cosb,
                       const float* __restrict__ sinb, float scale) {
    int gid  = blockIdx.x * blockDim.x + threadIdx.x;
    int row  = gid >> 8;
    int rem  = gid & 255;
    int h    = rem >> 3;
    int dblk = (rem & 7) * 8;
    int s    = row & (Sc - 1);
    __bf16* p = Q + (long)row * Hc + h * HDc;
    const float* cp = cosb + s * HDc;
    const float* sp = sinb + s * HDc;
    bf16x8 lo = *(bf16x8*)(p + dblk);
    bf16x8 hi = *(bf16x8*)(p + dblk + 64);
    bf16x8 olo, ohi;
#pragma unroll
    for (int j = 0; j < 8; ++j) {
        float ql = (float)lo[j], qh = (float)hi[j];
        float cl = cp[dblk + j],      sl = sp[dblk + j];
        float ch = cp[dblk + 64 + j], sh = sp[dblk + 64 + j];
        olo[j] = (__bf16)((ql * cl - qh * sl) * scale);
        ohi[j] = (__bf16)((qh * ch + ql * sh) * scale);
    }
    *(bf16x8*)(p + dblk)      = olo;
    *(bf16x8*)(p + dblk + 64) = ohi;
}

__global__ void rope_k(__bf16* __restrict__ KV, const float* __restrict__ cosb,
                       const float* __restrict__ sinb) {
    int gid  = blockIdx.x * blockDim.x + threadIdx.x;
    int row  = gid >> 3;
    int dblk = (gid & 7) * 8;
    int s    = row & (Sc - 1);
    __bf16* p = KV + (long)row * 256;
    const float* cp = cosb + s * HDc;
    const float* sp = sinb + s * HDc;
    bf16x8 lo = *(bf16x8*)(p + dblk);
    bf16x8 hi = *(bf16x8*)(p + dblk + 64);
    bf16x8 olo, ohi;
#pragma unroll
    for (int j = 0; j < 8; ++j) {
        float ql = (float)lo[j], qh = (float)hi[j];
        float cl = cp[dblk + j],      sl = sp[dblk + j];
        float ch = cp[dblk + 64 + j], sh = sp[dblk + 64 + j];
        olo[j] = (__bf16)(ql * cl - qh * sl);
        ohi[j] = (__bf16)(qh * ch + ql * sh);
    }
    *(bf16x8*)(p + dblk)      = olo;
    *(bf16x8*)(p + dblk + 64) = ohi;
}

// V transpose via LDS tile: Vt[b][d][s] = KV[(b*S+s)*256 + 128 + d]
// grid: (B * S/64) blocks, 256 thr. Coalesced global reads and writes.
__global__ void vtrans(const __bf16* __restrict__ KV, __bf16* __restrict__ Vt) {
    __shared__ __bf16 T[128][72];
    const int tid = threadIdx.x;
    const int s0  = (blockIdx.x & (Sc / 64 - 1)) * 64;
    const int b   = blockIdx.x / (Sc / 64);
#pragma unroll
    for (int i = 0; i < 4; ++i) {
        int e = i * 256 + tid;          // 0..1023
        int s = e >> 4, dc = (e & 15) * 8;
        bf16x8 v = *(const bf16x8*)(KV + (long)(b * Sc + s0 + s) * 256 + 128 + dc);
#pragma unroll
        for (int j = 0; j < 8; ++j) T[dc + j][s] = v[j];
    }
    __syncthreads();
#pragma unroll
    for (int i = 0; i < 4; ++i) {
        int e = i * 256 + tid;
        int d = e >> 3, sc8 = (e & 7) * 8;
        bf16x8 v;
#pragma unroll
        for (int j = 0; j < 8; ++j) v[j] = T[d][sc8 + j];
        *(bf16x8*)(Vt + (long)(b * HDc + d) * Sc + s0 + sc8) = v;
    }
}

// ---------------------------------------------------------------------------
// Causal MQA flash attention v3: single-barrier double-buffered async pipeline.
// grid (S/128, B*NH), heavy-qt-first. 4 waves x 32 q rows. KV tiles of 64.
// gll16 staging with XOR-swizzled LDS; K-frags hoisted across both q halves;
// row-sum l via ones-rows MFMA.
// ---------------------------------------------------------------------------
__global__ __launch_bounds__(256, 2)
void attn(const __bf16* __restrict__ Q,    // (B*S, H), rope'd & pre-scaled
          const __bf16* __restrict__ KV,   // (B*S, 256): cols 0..127 = K (rope'd)
          const __bf16* __restrict__ Vt,   // (B, HD, S)
          __bf16* __restrict__ O) {        // (B*S, H)
    const int qt   = (gridDim.x - 1) - blockIdx.x;   // heavy blocks first
    const int bh   = blockIdx.y;
    const int b    = bh >> 5, h = bh & 31;
    const int tid  = threadIdx.x;
    const int wave = tid >> 6, lane = tid & 63;
    const int lrow = lane & 15, quad = lane >> 4;

    __shared__ __bf16 Ks[2][64][128];   // swizzled: phys col16 = logical ^ (row&15)
    __shared__ __bf16 Vs[2][128][64];   // swizzled: phys col16 = logical ^ (row&7)
    __shared__ __bf16 Vones[16][72];
    __shared__ __bf16 Ps[4][16][72];

    for (int idx = tid; idx < 16 * 72; idx += 256)
        Vones[idx / 72][idx % 72] = (__bf16)1.0f;

    const int q0 = qt * 128 + wave * 32;

    bf16x8 aq[2][4];
#pragma unroll
    for (int qq = 0; qq < 2; ++qq) {
        const __bf16* qp = Q + (long)(b * Sc + q0 + qq * 16 + lrow) * Hc + h * HDc + quad * 8;
#pragma unroll
        for (int c = 0; c < 4; ++c) aq[qq][c] = *(const bf16x8*)(qp + c * 32);
    }

    f32x4 o[2][8] = {};
    f32x4 lac[2] = {};
    float mst[2][4];
#pragma unroll
    for (int qq = 0; qq < 2; ++qq)
#pragma unroll
        for (int r = 0; r < 4; ++r) mst[qq][r] = -3.0e38f;

    // staging address precompute
    const __bf16* kvb = KV + (long)b * Sc * 256;
    const __bf16* vtb = Vt + (long)b * HDc * Sc;
    int krow[4], kcol[4], vrow[4], vcol[4];
#pragma unroll
    for (int it = 0; it < 4; ++it) {
        int e = (wave * 4 + it) * 1024 + lane * 16;  // byte slot in 16KB tile
        int rk = e >> 8, cbk = (e >> 4) & 15;        // K: 256B rows
        krow[it] = rk; kcol[it] = ((cbk ^ (rk & 15)) * 8);
        int rv = e >> 7, cbv = (e >> 4) & 7;         // V: 128B rows
        vrow[it] = rv; vcol[it] = ((cbv ^ (rv & 7)) * 8);
    }

    auto stage = [&](int kt, int bu) {
#pragma unroll
        for (int it = 0; it < 4; ++it) {
            gll16(kvb + (long)(kt * 64 + krow[it]) * 256 + kcol[it],
                  &Ks[bu][0][0] + (wave * 4 + it) * 512, lane);
            gll16(vtb + (long)vrow[it] * Sc + kt * 64 + vcol[it],
                  &Vs[bu][0][0] + (wave * 4 + it) * 512, lane);
        }
    };

    const int nt = 2 * qt + 2;
    stage(0, 0);

    for (int kt = 0; kt < nt; ++kt) {
        __syncthreads();                       // drains vmcnt -> tile kt ready
        if (kt + 1 < nt) stage(kt + 1, (kt + 1) & 1);   // async prefetch
        const int bu = kt & 1;

        // S = Q K^T, K-frags shared across both q halves
        f32x4 sc[2][4] = {};
#pragma unroll
        for (int ct = 0; ct < 4; ++ct) {
#pragma unroll
            for (int c = 0; c < 4; ++c) {
                bf16x8 bk = *(const bf16x8*)&Ks[bu][ct * 16 + lrow][(((c << 2) | quad) ^ lrow) << 3];
                sc[0][ct] = __builtin_amdgcn_mfma_f32_16x16x32_bf16(aq[0][c], bk, sc[0][ct], 0, 0, 0);
                sc[1][ct] = __builtin_amdgcn_mfma_f32_16x16x32_bf16(aq[1][c], bk, sc[1][ct], 0, 0, 0);
            }
        }

        bf16x8 ap[2][2];
#pragma unroll
        for (int qq = 0; qq < 2; ++qq) {
            if (kt * 64 + 63 > q0 + qq * 16) {  // tile may cross the diagonal
#pragma unroll
                for (int ct = 0; ct < 4; ++ct) {
                    int kv = kt * 64 + ct * 16 + lrow;
#pragma unroll
                    for (int r = 0; r < 4; ++r) {
                        int qr = q0 + qq * 16 + quad * 4 + r;
                        if (kv > qr) sc[qq][ct][r] = -3.0e38f;
                    }
                }
            }

            float mnewv[4], alf[4];
#pragma unroll
            for (int r = 0; r < 4; ++r) {
                float mx = fmaxf(fmaxf(sc[qq][0][r], sc[qq][1][r]), fmaxf(sc[qq][2][r], sc[qq][3][r]));
#pragma unroll
                for (int off = 1; off < 16; off <<= 1) mx = fmaxf(mx, __shfl_xor(mx, off, 64));
                float mnew = fmaxf(mst[qq][r], mx);
                alf[r]   = __expf(mst[qq][r] - mnew);
                mst[qq][r] = mnew;
                mnewv[r] = mnew;
            }
#pragma unroll
            for (int ct = 0; ct < 4; ++ct)
#pragma unroll
                for (int r = 0; r < 4; ++r)
                    sc[qq][ct][r] = __expf(sc[qq][ct][r] - mnewv[r]);
#pragma unroll
            for (int dt = 0; dt < 8; ++dt)
#pragma unroll
                for (int r = 0; r < 4; ++r) o[qq][dt][r] *= alf[r];
#pragma unroll
            for (int r = 0; r < 4; ++r) lac[qq][r] *= alf[r];

            // P -> LDS (C-layout -> A-layout), per-wave buffer
#pragma unroll
            for (int ct = 0; ct < 4; ++ct)
#pragma unroll
                for (int r = 0; r < 4; ++r)
                    Ps[wave][quad * 4 + r][ct * 16 + lrow] = (__bf16)sc[qq][ct][r];
#pragma unroll
            for (int ks = 0; ks < 2; ++ks)
                ap[qq][ks] = *(const bf16x8*)&Ps[wave][lrow][ks * 32 + quad * 8];
        }

        // O += P V  (V-frags shared across both q halves)
#pragma unroll
        for (int dt = 0; dt < 8; ++dt) {
#pragma unroll
            for (int ks = 0; ks < 2; ++ks) {
                bf16x8 bv = *(const bf16x8*)&Vs[bu][dt * 16 + lrow]
                                [(((ks << 2) | quad) ^ (lrow & 7)) << 3];
#pragma unroll
                for (int qq = 0; qq < 2; ++qq)
                    o[qq][dt] = __builtin_amdgcn_mfma_f32_16x16x32_bf16(ap[qq][ks], bv, o[qq][dt], 0, 0, 0);
            }
        }
        // l += P . ones
#pragma unroll
        for (int ks = 0; ks < 2; ++ks) {
            bf16x8 bv = *(const bf16x8*)&Vones[lrow][ks * 32 + quad * 8];
#pragma unroll
            for (int qq = 0; qq < 2; ++qq)
                lac[qq] = __builtin_amdgcn_mfma_f32_16x16x32_bf16(ap[qq][ks], bv, lac[qq], 0, 0, 0);
        }
    }

    // epilogue
#pragma unroll
    for (int qq = 0; qq < 2; ++qq)
#pragma unroll
        for (int r = 0; r < 4; ++r) {
            float inv = 1.f / lac[qq][r];
            int qr = q0 + qq * 16 + quad * 4 + r;
            __bf16* op = O + (long)(b * Sc + qr) * Hc + h * HDc;
#pragma unroll
            for (int dt = 0; dt < 8; ++dt) op[dt * 16 + lrow] = (__bf16)(o[qq][dt][r] * inv);
        }
}

// ---------------------------------------------------------------------------
extern "C" void kernel_launch(void* const* d_in, const int* in_sizes, int n_in,
                              void* d_out, int out_size, void* d_ws, size_t ws_size,
                              hipStream_t stream) {
    const float* hs   = (const float*)d_in[0];
    const float* cosb = (const float*)d_in[1];
    const float* sinb = (const float*)d_in[2];
    const float* Wq   = (const float*)d_in[3];
    const float* Wk   = (const float*)d_in[4];
    const float* Wv   = (const float*)d_in[5];
    const float* Wd   = (const float*)d_in[6];
    float* out = (float*)d_out;

    char* ws = (char*)d_ws;
    const long SZ_HS  = (long)Bc * Sc * Hc * 2;      // 32MB
    const long SZ_W   = (long)Hc * Hc * 2;           // 32MB
    const long SZ_KV  = (long)Bc * Sc * 256 * 2;     // 2MB
    __bf16* hs16  = (__bf16*)(ws);
    __bf16* wq16  = (__bf16*)(ws + SZ_HS);
    __bf16* wkv16 = (__bf16*)(ws + SZ_HS + SZ_W);
    __bf16* q16   = (__bf16*)(ws + SZ_HS + SZ_W + SZ_KV);
    __bf16* kv16  = (__bf16*)(ws + SZ_HS + SZ_W + SZ_KV + SZ_HS);
    __bf16* vt16  = (__bf16*)(ws + SZ_HS + SZ_W + SZ_KV + SZ_HS + SZ_KV);
    __bf16* att16 = hs16;   // reuse: hidden dead after Q/KV GEMMs
    __bf16* wd16  = wq16;   // reuse: Wq dead after Q GEMM

    const int nHS = Bc * Sc * Hc;   // 16M
    const int nW  = Hc * Hc;        // 16M

    cvt_f32_bf16<<<nHS / 1024, 256, 0, stream>>>(hs, hs16, nHS);
    cvt_f32_bf16<<<nW / 1024, 256, 0, stream>>>(Wq, wq16, nW);
    build_wkv<<<(256 * Hc) / 1024, 256, 0, stream>>>(Wk, Wv, wkv16);

    gemm_bt<__bf16><<<dim3(Hc / 128, (Bc * Sc) / 128), 256, 0, stream>>>(
        hs16, wq16, q16, Bc * Sc, Hc, Hc);
    gemm_bt64<__bf16><<<dim3(256 / 64, (Bc * Sc) / 64), 256, 0, stream>>>(
        hs16, wkv16, kv16, Bc * Sc, 256, Hc);

    cvt_f32_bf16<<<nW / 1024, 256, 0, stream>>>(Wd, wd16, nW);  // after Q GEMM

    const float scale = 0.08838834764831845f;  // 1/sqrt(128)
    rope_q<<<(Bc * Sc * NHc * 8) / 256, 256, 0, stream>>>(q16, cosb, sinb, scale);
    rope_k<<<(Bc * Sc * 8) / 256, 256, 0, stream>>>(kv16, cosb, sinb);
    vtrans<<<Bc * (Sc / 64), 256, 0, stream>>>(kv16, vt16);

    attn<<<dim3(Sc / 128, Bc * NHc), 256, 0, stream>>>(q16, kv16, vt16, att16);

    gemm_bt<float><<<dim3(Hc / 128, (Bc * Sc) / 128), 256, 0, stream>>>(
        att16, wd16, out, Bc * Sc, Hc, Hc);
}